// Round 8
// baseline (629.187 us; speedup 1.0000x reference)
//
#include <hip/hip_runtime.h>
#include <hip/hip_cooperative_groups.h>
#include <hip/hip_bf16.h>
#include <stdint.h>

namespace cg = cooperative_groups;

// Problem constants (from reference)
#define B_ 8
#define T_ 1500
#define H_ 1280
#define HM1 1279
#define OUT_ 4096
#define MTOK 375
#define MROWS (B_*MTOK)   // 3000
#define KPAD 1280         // shared K for both GEMMs (cif K=1279 zero-padded)
#define GRID_ 512         // 2 blocks/CU co-resident (cooperative launch)

typedef __attribute__((ext_vector_type(8))) short bf16x8;  // 8 bf16 = 4 VGPRs
typedef __attribute__((ext_vector_type(4))) float f32x4;
typedef unsigned short u16;

static __device__ __forceinline__ u16 f2bf(float f) {
    unsigned int x = __float_as_uint(f);
    unsigned int r = (x + 0x7fffu + ((x >> 16) & 1u)) >> 16;
    return (u16)r;
}
static __device__ __forceinline__ float bf2f(u16 u) {
    return __uint_as_float(((unsigned int)u) << 16);
}
static __device__ __forceinline__ void glds16(const u16* g, u16* l) {
    __builtin_amdgcn_global_load_lds(
        (const __attribute__((address_space(1))) void*)g,
        (__attribute__((address_space(3))) void*)l, 16, 0, 0);
}

// One TMx128 output tile, BK=32, 256 threads (round-6 proven structure).
// XOR-swizzled LDS k-slots (4 slots of 8 elems per 32-elem row).
template<int TM, bool BF16_OUT>
static __device__ __forceinline__ void gemm_tile(
    const u16* __restrict__ A, const u16* __restrict__ Bt,
    const float* __restrict__ bias, void* __restrict__ Cv,
    int M, int N, int m0, int n0, u16* sA, u16* sB, int tid)
{
    constexpr int K = KPAD;
    constexpr int RA = TM / 64;            // A staging rounds (256 thr x 8 elems = 64 rows)
    constexpr int MI = 4;
    constexpr int NI = (TM == 128) ? 4 : 2;
    const int wave = tid >> 6, lane = tid & 63;
    const int wm = (TM == 128) ? (wave & 1) * 64 : 0;
    const int wn = (TM == 128) ? (wave >> 1) * 64 : wave * 32;
    const int lrow = lane & 15, quad = lane >> 4;

    const int r0 = tid >> 2, sl = tid & 3;
    const int q0 = sl ^ (r0 & 3) ^ ((r0 >> 2) & 3);
    const u16* Ag[RA];
    #pragma unroll
    for (int p = 0; p < RA; ++p)
        Ag[p] = A + (size_t)min(m0 + r0 + 64*p, M - 1) * K + q0 * 8;
    const u16* Bg[2];
    #pragma unroll
    for (int p = 0; p < 2; ++p)
        Bg[p] = Bt + (size_t)(n0 + r0 + 64*p) * K + q0 * 8;

    int offA[MI], offB[NI];
    #pragma unroll
    for (int i = 0; i < MI; ++i) {
        int m = wm + i*16 + lrow;
        offA[i] = m*32 + (quad ^ (m & 3) ^ ((m >> 2) & 3)) * 8;
    }
    #pragma unroll
    for (int i = 0; i < NI; ++i) {
        int n = wn + i*16 + lrow;
        offB[i] = n*32 + (quad ^ (n & 3) ^ ((n >> 2) & 3)) * 8;
    }

    f32x4 acc[MI][NI] = {};

    for (int k0 = 0; k0 < K; k0 += 32) {
        #pragma unroll
        for (int p = 0; p < RA; ++p) glds16(Ag[p] + k0, sA + (tid + 256*p)*8);
        #pragma unroll
        for (int p = 0; p < 2;  ++p) glds16(Bg[p] + k0, sB + (tid + 256*p)*8);
        __syncthreads();
        bf16x8 af[MI], bfr[NI];
        #pragma unroll
        for (int i = 0; i < MI; ++i) af[i]  = *(const bf16x8*)&sA[offA[i]];
        #pragma unroll
        for (int i = 0; i < NI; ++i) bfr[i] = *(const bf16x8*)&sB[offB[i]];
        #pragma unroll
        for (int mi = 0; mi < MI; ++mi)
            #pragma unroll
            for (int ni = 0; ni < NI; ++ni)
                acc[mi][ni] = __builtin_amdgcn_mfma_f32_16x16x32_bf16(
                    af[mi], bfr[ni], acc[mi][ni], 0, 0, 0);
        __syncthreads();
    }

    // epilogue: C/D layout col=lane&15, row=quad*4+reg
    #pragma unroll
    for (int ni = 0; ni < NI; ++ni) {
        int col = n0 + wn + ni*16 + lrow;
        float bv = bias[col];
        #pragma unroll
        for (int mi = 0; mi < MI; ++mi) {
            int rowb = m0 + wm + mi*16 + quad*4;
            #pragma unroll
            for (int r = 0; r < 4; ++r) {
                int row = rowb + r;
                if (row < M) {
                    float v = acc[mi][ni][r] + bv;
                    if (BF16_OUT) ((u16*)Cv)[(size_t)row*N + col] = f2bf(v);
                    else          ((float*)Cv)[(size_t)row*N + col] = v;
                }
            }
        }
    }
}

// Single cooperative kernel: all phases, grid.sync() between them.
__global__ __launch_bounds__(256, 2) void k_mega(
    const float* __restrict__ audio, const int* __restrict__ num_tokens,
    const float* __restrict__ rms_w,
    const float* __restrict__ cif_w, const float* __restrict__ cif_b,
    const float* __restrict__ text_w, const float* __restrict__ text_b,
    float* __restrict__ out, float* __restrict__ pred_out,
    int* __restrict__ tok0, float* __restrict__ w0a,
    int* __restrict__ tok1, float* __restrict__ w1a,
    int* __restrict__ lo, int* __restrict__ hi,
    u16* __restrict__ h1b, u16* __restrict__ cwt, u16* __restrict__ twt,
    u16* __restrict__ hX)
{
    cg::grid_group grid = cg::this_grid();
    __shared__ __align__(16) char smem_raw[16384];
    const int tid = threadIdx.x;
    const int bid = blockIdx.x;
    const int G = GRID_;

    // ================= Phase A: scan (blocks 0..7) + weight transposes =======
    if (bid < B_) {
        const int b = bid;
        float* smem = (float*)smem_raw;
        float* al = smem;                    // [1500]
        float* ip = smem + 1500;             // [1500]
        float* red = smem + 3000;            // [256]
        int*   redI = (int*)(smem + 3256);   // [256]
        float* scale_sh = smem + 3512;

        // phase 1: sigmoid + pred + scale
        float sig[6];
        float s = 0.f;
        #pragma unroll
        for (int i = 0; i < 6; ++i) {
            int t = tid + i*256;
            sig[i] = 0.f;
            if (t < T_) {
                float x = audio[((size_t)b*T_ + t)*H_ + (H_-1)];
                sig[i] = 1.f / (1.f + expf(-x));
                s += sig[i];
            }
        }
        red[tid] = s; __syncthreads();
        for (int off = 128; off > 0; off >>= 1) {
            if (tid < off) red[tid] += red[tid+off];
            __syncthreads();
        }
        if (tid == 0) {
            float pred = red[0];
            pred_out[b] = pred;
            *scale_sh = (float)num_tokens[b] / pred;
        }
        __syncthreads();
        float scale = *scale_sh;
        #pragma unroll
        for (int i = 0; i < 6; ++i) {
            int t = tid + i*256;
            if (t < T_) al[t] = sig[i] * scale;
        }
        for (int m = tid; m < MTOK; m += 256) {
            lo[b*MTOK+m] = T_; hi[b*MTOK+m] = 0;
        }
        if (tid == 0) lo[b*MTOK] = 0;
        __syncthreads();

        // phase 2: serial carry chain (lane 0), LDS-only emissions
        if (tid == 0) {
            float integ = 0.f;
            float4 cur = *(const float4*)&al[0];
            for (int t = 0; t < T_; t += 4) {
                float4 nxt = (t + 4 < T_) ? *(const float4*)&al[t+4]
                                          : make_float4(0.f,0.f,0.f,0.f);
                float av[4] = {cur.x, cur.y, cur.z, cur.w};
                float ipv[4];
                #pragma unroll
                for (int j = 0; j < 4; ++j) {
                    ipv[j] = integ;
                    float sx = integ + av[j];
                    integ = (sx >= 1.f) ? (sx - 1.f) : sx;
                }
                *(float4*)&ip[t] = *(float4*)ipv;
                cur = nxt;
            }
        }
        __syncthreads();

        // phase 3: parallel post-pass
        const int t0 = tid * 6;
        const int nm1 = num_tokens[b] - 1;
        int fires[6];
        int cnt = 0;
        if (t0 < T_) {
            #pragma unroll
            for (int j = 0; j < 6; ++j) {
                int t = t0 + j;
                float sx = ip[t] + al[t];     // same fp32 add as serial scan
                fires[j] = (sx >= 1.f) ? 1 : 0;
                cnt += fires[j];
            }
        }
        redI[tid] = cnt; __syncthreads();
        #pragma unroll
        for (int off = 1; off < 256; off <<= 1) {
            int v = redI[tid];
            if (tid >= off) v += redI[tid - off];
            __syncthreads();
            redI[tid] = v;
            __syncthreads();
        }
        if (t0 < T_) {
            int F = redI[tid] - cnt;
            const int base = b*T_;
            #pragma unroll
            for (int j = 0; j < 6; ++j) {
                int t = t0 + j;
                float a = al[t], ipv = ip[t];
                int fire = fires[j];
                F += fire;
                int tk1 = min(F, nm1);
                int tk0 = min(F - fire, nm1);
                float w0 = fire ? (1.f - ipv) : a;
                float w1 = (t < T_-1) ? (a - w0) : 0.f;
                tok0[base+t] = tk0;  w0a[base+t] = w0;
                tok1[base+t] = tk1;  w1a[base+t] = w1;
                if (tk1 != tk0) {
                    hi[b*MTOK + tk0] = t + 1;
                    lo[b*MTOK + tk1] = t;
                }
                if (t == T_-1) hi[b*MTOK + tk1] = T_;
            }
        }
    } else {
        // transpose tiles, strided over blocks 8..G-1
        float (*tile)[33] = (float(*)[33])smem_raw;
        for (int idx = bid - B_; idx < 6720; idx += G - B_) {
            int blk = idx;
            const float* src; u16* dst; int R, C, bx, by;
            if (blk < 1600) { src = cif_w;  dst = cwt; R = HM1; C = H_;   bx = blk % 40;  by = blk / 40; }
            else { blk -= 1600; src = text_w; dst = twt; R = H_;  C = OUT_; bx = blk % 128; by = blk / 128; }
            int c0 = bx * 32, r0 = by * 32;
            int lx = tid & 31, ly = tid >> 5;  // 32 x 8
            #pragma unroll
            for (int j = 0; j < 4; ++j) {
                int r = r0 + ly + j*8;
                tile[ly + j*8][lx] = (r < R) ? src[(size_t)r*C + c0 + lx] : 0.f;
            }
            __syncthreads();
            #pragma unroll
            for (int j = 0; j < 4; ++j) {
                int c = c0 + ly + j*8;
                dst[(size_t)c*KPAD + r0 + lx] = f2bf(tile[lx][ly + j*8]);
            }
            __syncthreads();
        }
    }
    grid.sync();

    // ================= Phase B: sparse pooling -> h1b bf16 ===================
    for (int bm = bid; bm < MROWS; bm += G) {
        int b = bm / MTOK, m = bm % MTOK;
        int l = lo[bm], h = hi[bm];
        float acc[5] = {0.f,0.f,0.f,0.f,0.f};
        for (int t = l; t < h; ++t) {
            int i0 = b*T_ + t;
            float w = 0.f;
            if (tok0[i0] == m) w += w0a[i0];
            if (tok1[i0] == m) w += w1a[i0];
            if (w != 0.f) {
                const float* row = audio + (size_t)i0 * H_;
                #pragma unroll
                for (int i = 0; i < 5; ++i) {
                    int d = tid + i*256;
                    if (d < HM1) acc[i] += w * row[d];
                }
            }
        }
        u16* dst = h1b + (size_t)bm * KPAD;
        #pragma unroll
        for (int i = 0; i < 5; ++i) {
            int d = tid + i*256;
            dst[d] = (d < HM1) ? f2bf(acc[i]) : (u16)0;
        }
    }
    grid.sync();

    // ================= Phase C: cif_proj (64x128 tiles, bf16 out) ============
    if (bid < 470) {
        int by = bid / 10, bx = bid % 10;
        gemm_tile<64, true>(h1b, cwt, cif_b, hX, MROWS, H_,
                            by*64, bx*128,
                            (u16*)smem_raw, (u16*)(smem_raw + 4096), tid);
    }
    grid.sync();

    // ================= Phase D: RMSNorm in-place on hX bf16 ==================
    {
        float* red = (float*)smem_raw;
        for (int row = bid; row < MROWS; row += G) {
            u16* p = hX + (size_t)row * H_;
            float v[5];
            float s = 0.f;
            #pragma unroll
            for (int i = 0; i < 5; ++i) {
                v[i] = bf2f(p[tid + i*256]);
                s += v[i] * v[i];
            }
            red[tid] = s; __syncthreads();
            for (int off = 128; off > 0; off >>= 1) {
                if (tid < off) red[tid] += red[tid+off];
                __syncthreads();
            }
            float inv = 1.f / sqrtf(red[0] / (float)H_ + 1e-6f);
            #pragma unroll
            for (int i = 0; i < 5; ++i) {
                int d = tid + i*256;
                p[d] = f2bf(v[i] * inv * rms_w[d]);
            }
            __syncthreads();
        }
    }
    grid.sync();

    // ================= Phase E: text_proj (128x128 tiles, fp32 out) ==========
    for (int tile = bid; tile < 32*24; tile += G) {
        int bx = tile & 31, by = tile >> 5;
        gemm_tile<128, false>(hX, twt, text_b, out, MROWS, OUT_,
                              by*128, bx*128,
                              (u16*)smem_raw, (u16*)(smem_raw + 8192), tid);
    }
}

extern "C" void kernel_launch(void* const* d_in, const int* in_sizes, int n_in,
                              void* d_out, int out_size, void* d_ws, size_t ws_size,
                              hipStream_t stream) {
    (void)in_sizes; (void)n_in; (void)out_size; (void)ws_size;
    const float* audio      = (const float*)d_in[0];
    const int*   num_tokens = (const int*)d_in[1];
    const float* rms_w      = (const float*)d_in[2];
    const float* cif_w      = (const float*)d_in[3];
    const float* cif_b      = (const float*)d_in[4];
    const float* text_w     = (const float*)d_in[5];
    const float* text_b     = (const float*)d_in[6];

    float* out  = (float*)d_out;                   // fp32 output
    float* pred = out + (size_t)MROWS * OUT_;      // pred_num_tokens tail (8 floats)

    char* ws = (char*)d_ws;
    float* w0a  = (float*)(ws + 48000);
    float* w1a  = (float*)(ws + 96000);
    int*   tok0 = (int*)  (ws + 144000);
    int*   tok1 = (int*)  (ws + 192000);
    int*   lo   = (int*)  (ws + 240000);
    int*   hi   = (int*)  (ws + 252000);
    // DISJOINT regions (no lifetime aliasing):
    u16* h1b = (u16*)(ws + 264192);     //  7,680,000 B
    u16* cwt = (u16*)(ws + 7944192);    //  3,276,800 B
    u16* twt = (u16*)(ws + 11220992);   // 10,485,760 B
    u16* hX  = (u16*)(ws + 21706752);   //  7,680,000 B
    // total ws usage: 29,386,752 B

    void* args[] = {
        (void*)&audio, (void*)&num_tokens, (void*)&rms_w,
        (void*)&cif_w, (void*)&cif_b, (void*)&text_w, (void*)&text_b,
        (void*)&out, (void*)&pred,
        (void*)&tok0, (void*)&w0a, (void*)&tok1, (void*)&w1a,
        (void*)&lo, (void*)&hi,
        (void*)&h1b, (void*)&cwt, (void*)&twt, (void*)&hX
    };
    hipLaunchCooperativeKernel((const void*)k_mega, dim3(GRID_), dim3(256),
                               args, 0, stream);
}

// Round 9
// 276.968 us; speedup vs baseline: 2.2717x; 2.2717x over previous
//
#include <hip/hip_runtime.h>
#include <hip/hip_bf16.h>
#include <stdint.h>

// Problem constants (from reference)
#define B_ 8
#define T_ 1500
#define H_ 1280
#define HM1 1279
#define OUT_ 4096
#define MTOK 375
#define MROWS (B_*MTOK)   // 3000
#define KPAD 1280         // shared K for both GEMMs (cif K=1279 zero-padded)

typedef __attribute__((ext_vector_type(8))) short bf16x8;  // 8 bf16 = 4 VGPRs
typedef __attribute__((ext_vector_type(4))) float f32x4;
typedef unsigned short u16;

static __device__ __forceinline__ u16 f2bf(float f) {
    unsigned int x = __float_as_uint(f);
    unsigned int r = (x + 0x7fffu + ((x >> 16) & 1u)) >> 16;
    return (u16)r;
}
static __device__ __forceinline__ void glds16(const u16* g, u16* l) {
    __builtin_amdgcn_global_load_lds(
        (const __attribute__((address_space(1))) void*)g,
        (__attribute__((address_space(3))) void*)l, 16, 0, 0);
}

// Front kernel: blocks 0..7 = fused sigmoid+scan+post-pass (one per batch);
// blocks 8.. = both weight transposes (text transpose folds in rms_w).
__global__ __launch_bounds__(256) void k_front(
    const float* __restrict__ audio, const int* __restrict__ num_tokens,
    const float* __restrict__ rms_w,
    float* __restrict__ pred_out,
    int* __restrict__ tok0, float* __restrict__ w0a,
    int* __restrict__ tok1, float* __restrict__ w1a,
    int* __restrict__ lo, int* __restrict__ hi,
    float* __restrict__ h_sumsq,
    const float* __restrict__ cif_w, const float* __restrict__ text_w,
    u16* __restrict__ cwt, u16* __restrict__ twt)
{
    __shared__ float smem[3514];   // union: scan(3513 floats) / transpose tile(32x33)
    const int tid = threadIdx.x;

    if (blockIdx.x < B_) {
        // ================= CIF scan branch =================
        const int b = blockIdx.x;
        float* al = smem;                    // [1500]
        float* ip = smem + 1500;             // [1500]
        float* red = smem + 3000;            // [256]
        int*   redI = (int*)(smem + 3256);   // [256]
        float* scale_sh = smem + 3512;

        // phase 1: sigmoid + pred + scale
        float sig[6];
        float s = 0.f;
        #pragma unroll
        for (int i = 0; i < 6; ++i) {
            int t = tid + i*256;
            sig[i] = 0.f;
            if (t < T_) {
                float x = audio[((size_t)b*T_ + t)*H_ + (H_-1)];
                sig[i] = 1.f / (1.f + expf(-x));
                s += sig[i];
            }
        }
        red[tid] = s; __syncthreads();
        for (int off = 128; off > 0; off >>= 1) {
            if (tid < off) red[tid] += red[tid+off];
            __syncthreads();
        }
        if (tid == 0) {
            float pred = red[0];
            pred_out[b] = pred;
            *scale_sh = (float)num_tokens[b] / pred;
        }
        __syncthreads();
        float scale = *scale_sh;
        #pragma unroll
        for (int i = 0; i < 6; ++i) {
            int t = tid + i*256;
            if (t < T_) al[t] = sig[i] * scale;
        }
        for (int m = tid; m < MTOK; m += 256) {
            lo[b*MTOK+m] = T_; hi[b*MTOK+m] = 0;
            h_sumsq[b*MTOK+m] = 0.f;         // zero for cif-epilogue atomics
        }
        if (tid == 0) lo[b*MTOK] = 0;
        __syncthreads();

        // phase 2: serial carry chain (lane 0), LDS-only emissions
        if (tid == 0) {
            float integ = 0.f;
            float4 cur = *(const float4*)&al[0];
            for (int t = 0; t < T_; t += 4) {
                float4 nxt = (t + 4 < T_) ? *(const float4*)&al[t+4]
                                          : make_float4(0.f,0.f,0.f,0.f);
                float av[4] = {cur.x, cur.y, cur.z, cur.w};
                float ipv[4];
                #pragma unroll
                for (int j = 0; j < 4; ++j) {
                    ipv[j] = integ;
                    float sx = integ + av[j];
                    integ = (sx >= 1.f) ? (sx - 1.f) : sx;
                }
                *(float4*)&ip[t] = *(float4*)ipv;
                cur = nxt;
            }
        }
        __syncthreads();

        // phase 3: parallel post-pass
        const int t0 = tid * 6;
        const int nm1 = num_tokens[b] - 1;
        int fires[6];
        int cnt = 0;
        if (t0 < T_) {
            #pragma unroll
            for (int j = 0; j < 6; ++j) {
                int t = t0 + j;
                float sx = ip[t] + al[t];     // same fp32 add as serial scan
                fires[j] = (sx >= 1.f) ? 1 : 0;
                cnt += fires[j];
            }
        }
        redI[tid] = cnt; __syncthreads();
        #pragma unroll
        for (int off = 1; off < 256; off <<= 1) {
            int v = redI[tid];
            if (tid >= off) v += redI[tid - off];
            __syncthreads();
            redI[tid] = v;
            __syncthreads();
        }
        if (t0 < T_) {
            int F = redI[tid] - cnt;
            const int base = b*T_;
            #pragma unroll
            for (int j = 0; j < 6; ++j) {
                int t = t0 + j;
                float a = al[t], ipv = ip[t];
                int fire = fires[j];
                F += fire;
                int tk1 = min(F, nm1);
                int tk0 = min(F - fire, nm1);
                float w0 = fire ? (1.f - ipv) : a;
                float w1 = (t < T_-1) ? (a - w0) : 0.f;
                tok0[base+t] = tk0;  w0a[base+t] = w0;
                tok1[base+t] = tk1;  w1a[base+t] = w1;
                if (tk1 != tk0) {
                    hi[b*MTOK + tk0] = t + 1;
                    lo[b*MTOK + tk1] = t;
                }
                if (t == T_-1) hi[b*MTOK + tk1] = T_;
            }
        }
    } else {
        // ================= transpose branch =================
        float (*tile)[33] = (float(*)[33])smem;
        int blk = blockIdx.x - B_;
        const float* src; u16* dst; int R, C, bx, by; bool scaled;
        if (blk < 1600) { src = cif_w;  dst = cwt; R = HM1; C = H_;   bx = blk % 40;  by = blk / 40;  scaled = false; }
        else { blk -= 1600; src = text_w; dst = twt; R = H_;  C = OUT_; bx = blk % 128; by = blk / 128; scaled = true; }
        int c0 = bx * 32, r0 = by * 32;
        int lx = tid & 31, ly = tid >> 5;  // 32 x 8
        #pragma unroll
        for (int j = 0; j < 4; ++j) {
            int r = r0 + ly + j*8;
            tile[ly + j*8][lx] = (r < R) ? src[(size_t)r*C + c0 + lx] : 0.f;
        }
        __syncthreads();
        // write value = src[r0+lx][c0+ly+j*8]; its k-index is r0+lx -> fold rms_w
        float rw = scaled ? rms_w[r0 + lx] : 1.f;
        #pragma unroll
        for (int j = 0; j < 4; ++j) {
            int c = c0 + ly + j*8;
            dst[(size_t)c*KPAD + r0 + lx] = f2bf(tile[lx][ly + j*8] * rw);
        }
    }
}

// K3: sparse pooling -> h1b bf16 [MROWS][KPAD], col 1279 = 0
__global__ __launch_bounds__(256) void k3_pool(
    const float* __restrict__ audio,
    const int* __restrict__ tok0, const float* __restrict__ w0a,
    const int* __restrict__ tok1, const float* __restrict__ w1a,
    const int* __restrict__ lo, const int* __restrict__ hi,
    u16* __restrict__ h1b)
{
    int bm = blockIdx.x;
    int b = bm / MTOK, m = bm % MTOK;
    int l = lo[bm], h = hi[bm];
    int tid = threadIdx.x;
    float acc[5] = {0.f,0.f,0.f,0.f,0.f};
    for (int t = l; t < h; ++t) {
        int i0 = b*T_ + t;
        float w = 0.f;
        if (tok0[i0] == m) w += w0a[i0];
        if (tok1[i0] == m) w += w1a[i0];
        if (w != 0.f) {
            const float* row = audio + (size_t)i0 * H_;
            #pragma unroll
            for (int i = 0; i < 5; ++i) {
                int d = tid + i*256;
                if (d < HM1) acc[i] += w * row[d];
            }
        }
    }
    u16* dst = h1b + (size_t)bm * KPAD;
    #pragma unroll
    for (int i = 0; i < 5; ++i) {
        int d = tid + i*256;
        dst[d] = (d < HM1) ? f2bf(acc[i]) : (u16)0;
    }
}

// MFMA bf16 GEMM (B^T form), BK=32 (round-6 proven), 3 blocks/CU.
// CIF mode: bf16 out + per-row sum-of-squares atomics (pre-rounding fp32).
// TEXT mode: fp32 out, per-row 1/rms scale applied to acc (rms_w folded in Bt).
template<int TM, bool CIF>
__global__ __launch_bounds__(256, 3) void mfma_gemm_bt(
    const u16* __restrict__ A, const u16* __restrict__ Bt,
    const float* __restrict__ bias, void* __restrict__ Cv,
    float* __restrict__ h_sumsq, int M, int N)
{
    constexpr int K = KPAD;
    constexpr int RA = TM / 64;
    constexpr int MI = 4;
    constexpr int NI = (TM == 128) ? 4 : 2;
    __shared__ u16 sA[TM*32];
    __shared__ u16 sB[128*32];
    const int tid = threadIdx.x;
    const int m0 = blockIdx.y * TM, n0 = blockIdx.x * 128;
    const int wave = tid >> 6, lane = tid & 63;
    const int wm = (TM == 128) ? (wave & 1) * 64 : 0;
    const int wn = (TM == 128) ? (wave >> 1) * 64 : wave * 32;
    const int lrow = lane & 15, quad = lane >> 4;

    const int r0 = tid >> 2, sl = tid & 3;
    const int q0 = sl ^ (r0 & 3) ^ ((r0 >> 2) & 3);
    const u16* Ag[RA];
    #pragma unroll
    for (int p = 0; p < RA; ++p)
        Ag[p] = A + (size_t)min(m0 + r0 + 64*p, M - 1) * K + q0 * 8;
    const u16* Bg[2];
    #pragma unroll
    for (int p = 0; p < 2; ++p)
        Bg[p] = Bt + (size_t)(n0 + r0 + 64*p) * K + q0 * 8;

    int offA[MI], offB[NI];
    #pragma unroll
    for (int i = 0; i < MI; ++i) {
        int m = wm + i*16 + lrow;
        offA[i] = m*32 + (quad ^ (m & 3) ^ ((m >> 2) & 3)) * 8;
    }
    #pragma unroll
    for (int i = 0; i < NI; ++i) {
        int n = wn + i*16 + lrow;
        offB[i] = n*32 + (quad ^ (n & 3) ^ ((n >> 2) & 3)) * 8;
    }

    f32x4 acc[MI][NI] = {};

    for (int k0 = 0; k0 < K; k0 += 32) {
        #pragma unroll
        for (int p = 0; p < RA; ++p) glds16(Ag[p] + k0, sA + (tid + 256*p)*8);
        #pragma unroll
        for (int p = 0; p < 2;  ++p) glds16(Bg[p] + k0, sB + (tid + 256*p)*8);
        __syncthreads();
        bf16x8 af[MI], bfr[NI];
        #pragma unroll
        for (int i = 0; i < MI; ++i) af[i]  = *(const bf16x8*)&sA[offA[i]];
        #pragma unroll
        for (int i = 0; i < NI; ++i) bfr[i] = *(const bf16x8*)&sB[offB[i]];
        #pragma unroll
        for (int mi = 0; mi < MI; ++mi)
            #pragma unroll
            for (int ni = 0; ni < NI; ++ni)
                acc[mi][ni] = __builtin_amdgcn_mfma_f32_16x16x32_bf16(
                    af[mi], bfr[ni], acc[mi][ni], 0, 0, 0);
        __syncthreads();
    }

    // epilogue: C/D layout col=lane&15, row=quad*4+reg
    float bv[NI];
    #pragma unroll
    for (int ni = 0; ni < NI; ++ni) bv[ni] = bias[n0 + wn + ni*16 + lrow];

    #pragma unroll
    for (int mi = 0; mi < MI; ++mi) {
        #pragma unroll
        for (int r = 0; r < 4; ++r) {
            int row = m0 + wm + mi*16 + quad*4 + r;
            if (CIF) {
                float ss = 0.f;
                #pragma unroll
                for (int ni = 0; ni < NI; ++ni) {
                    float v = acc[mi][ni][r] + bv[ni];
                    ss += v * v;
                    if (row < M)
                        ((u16*)Cv)[(size_t)row*N + (n0 + wn + ni*16 + lrow)] = f2bf(v);
                }
                // reduce ss over the 16 lanes (lrow) sharing this row
                ss += __shfl_xor(ss, 1);
                ss += __shfl_xor(ss, 2);
                ss += __shfl_xor(ss, 4);
                ss += __shfl_xor(ss, 8);
                if (lrow == 0 && row < M) atomicAdd(&h_sumsq[row], ss);
            } else {
                float inv = 1.f;
                if (row < M)
                    inv = 1.f / sqrtf(h_sumsq[row] / (float)H_ + 1e-6f);
                #pragma unroll
                for (int ni = 0; ni < NI; ++ni) {
                    if (row < M)
                        ((float*)Cv)[(size_t)row*N + (n0 + wn + ni*16 + lrow)] =
                            acc[mi][ni][r] * inv + bv[ni];
                }
            }
        }
    }
}

extern "C" void kernel_launch(void* const* d_in, const int* in_sizes, int n_in,
                              void* d_out, int out_size, void* d_ws, size_t ws_size,
                              hipStream_t stream) {
    (void)in_sizes; (void)n_in; (void)out_size; (void)ws_size;
    const float* audio      = (const float*)d_in[0];
    const int*   num_tokens = (const int*)d_in[1];
    const float* rms_w      = (const float*)d_in[2];
    const float* cif_w      = (const float*)d_in[3];
    const float* cif_b      = (const float*)d_in[4];
    const float* text_w     = (const float*)d_in[5];
    const float* text_b     = (const float*)d_in[6];

    float* out  = (float*)d_out;                   // fp32 output
    float* pred = out + (size_t)MROWS * OUT_;      // pred_num_tokens tail (8 floats)

    char* ws = (char*)d_ws;
    float* h_sumsq = (float*)(ws + 0);         // 12000 B (zeroed in k_front)
    float* w0a  = (float*)(ws + 48000);
    float* w1a  = (float*)(ws + 96000);
    int*   tok0 = (int*)  (ws + 144000);
    int*   tok1 = (int*)  (ws + 192000);
    int*   lo   = (int*)  (ws + 240000);
    int*   hi   = (int*)  (ws + 252000);
    // DISJOINT regions (no lifetime aliasing):
    u16* h1b = (u16*)(ws + 264192);     //  7,680,000 B
    u16* cwt = (u16*)(ws + 7944192);    //  3,276,800 B
    u16* twt = (u16*)(ws + 11220992);   // 10,485,760 B  (rms_w folded in)
    u16* hX  = (u16*)(ws + 21706752);   //  7,680,000 B  (cif out, unnormalized)
    // total ws usage: 29,386,752 B

    // scan (blocks 0..7) + weight transposes (blocks 8..6727)
    k_front<<<B_ + 1600 + 5120, 256, 0, stream>>>(
        audio, num_tokens, rms_w, pred, tok0, w0a, tok1, w1a, lo, hi,
        h_sumsq, cif_w, text_w, cwt, twt);
    k3_pool<<<MROWS, 256, 0, stream>>>(audio, tok0, w0a, tok1, w1a, lo, hi, h1b);
    // cif_proj (bf16 out + row sumsq): hX = h1b . cwt^T + cif_b
    mfma_gemm_bt<64, true><<<dim3(H_/128, (MROWS+63)/64), 256, 0, stream>>>(
        h1b, cwt, cif_b, hX, h_sumsq, MROWS, H_);
    // text_proj (fp32 out, 1/rms applied in epilogue): out = norm(hX) . twt^T + text_b
    mfma_gemm_bt<128, false><<<dim3(OUT_/128, (MROWS+127)/128), 256, 0, stream>>>(
        hX, twt, text_b, out, h_sumsq, MROWS, OUT_);
}

// Round 10
// 250.265 us; speedup vs baseline: 2.5141x; 1.1067x over previous
//
#include <hip/hip_runtime.h>
#include <hip/hip_bf16.h>
#include <stdint.h>

// Problem constants (from reference)
#define B_ 8
#define T_ 1500
#define H_ 1280
#define HM1 1279
#define OUT_ 4096
#define MTOK 375
#define MROWS (B_*MTOK)   // 3000
#define KPAD 1280         // shared K for both GEMMs (cif K=1279 zero-padded)

typedef __attribute__((ext_vector_type(8))) short bf16x8;  // 8 bf16 = 4 VGPRs
typedef __attribute__((ext_vector_type(4))) float f32x4;
typedef unsigned short u16;

static __device__ __forceinline__ u16 f2bf(float f) {
    unsigned int x = __float_as_uint(f);
    unsigned int r = (x + 0x7fffu + ((x >> 16) & 1u)) >> 16;
    return (u16)r;
}
static __device__ __forceinline__ void glds16(const u16* g, u16* l) {
    __builtin_amdgcn_global_load_lds(
        (const __attribute__((address_space(1))) void*)g,
        (__attribute__((address_space(3))) void*)l, 16, 0, 0);
}

// Front kernel: blocks 0..7 = fused sigmoid+scan+post-pass (one per batch);
// blocks 8.. = both weight transposes (text transpose folds in rms_w).
__global__ __launch_bounds__(256) void k_front(
    const float* __restrict__ audio, const int* __restrict__ num_tokens,
    const float* __restrict__ rms_w,
    float* __restrict__ pred_out,
    int* __restrict__ tok0, float* __restrict__ w0a,
    int* __restrict__ tok1, float* __restrict__ w1a,
    int* __restrict__ lo, int* __restrict__ hi,
    float* __restrict__ h_sumsq,
    const float* __restrict__ cif_w, const float* __restrict__ text_w,
    u16* __restrict__ cwt, u16* __restrict__ twt)
{
    __shared__ float smem[3514];   // union: scan(3513 floats) / transpose tile(32x33)
    const int tid = threadIdx.x;

    if (blockIdx.x < B_) {
        // ================= CIF scan branch =================
        const int b = blockIdx.x;
        float* al = smem;                    // [1500]
        float* ip = smem + 1500;             // [1500]
        float* red = smem + 3000;            // [256]
        int*   redI = (int*)(smem + 3256);   // [256]
        float* scale_sh = smem + 3512;

        // phase 1: sigmoid + pred + scale
        float sig[6];
        float s = 0.f;
        #pragma unroll
        for (int i = 0; i < 6; ++i) {
            int t = tid + i*256;
            sig[i] = 0.f;
            if (t < T_) {
                float x = audio[((size_t)b*T_ + t)*H_ + (H_-1)];
                sig[i] = 1.f / (1.f + expf(-x));
                s += sig[i];
            }
        }
        red[tid] = s; __syncthreads();
        for (int off = 128; off > 0; off >>= 1) {
            if (tid < off) red[tid] += red[tid+off];
            __syncthreads();
        }
        if (tid == 0) {
            float pred = red[0];
            pred_out[b] = pred;
            *scale_sh = (float)num_tokens[b] / pred;
        }
        __syncthreads();
        float scale = *scale_sh;
        #pragma unroll
        for (int i = 0; i < 6; ++i) {
            int t = tid + i*256;
            if (t < T_) al[t] = sig[i] * scale;
        }
        for (int m = tid; m < MTOK; m += 256) {
            lo[b*MTOK+m] = T_; hi[b*MTOK+m] = 0;
            h_sumsq[b*MTOK+m] = 0.f;         // zero for cif-epilogue atomics
        }
        if (tid == 0) lo[b*MTOK] = 0;
        __syncthreads();

        // phase 2: serial carry chain (lane 0), LDS-only emissions
        if (tid == 0) {
            float integ = 0.f;
            float4 cur = *(const float4*)&al[0];
            for (int t = 0; t < T_; t += 4) {
                float4 nxt = (t + 4 < T_) ? *(const float4*)&al[t+4]
                                          : make_float4(0.f,0.f,0.f,0.f);
                float av[4] = {cur.x, cur.y, cur.z, cur.w};
                float ipv[4];
                #pragma unroll
                for (int j = 0; j < 4; ++j) {
                    ipv[j] = integ;
                    float sx = integ + av[j];
                    integ = (sx >= 1.f) ? (sx - 1.f) : sx;
                }
                *(float4*)&ip[t] = *(float4*)ipv;
                cur = nxt;
            }
        }
        __syncthreads();

        // phase 3: parallel post-pass
        const int t0 = tid * 6;
        const int nm1 = num_tokens[b] - 1;
        int fires[6];
        int cnt = 0;
        if (t0 < T_) {
            #pragma unroll
            for (int j = 0; j < 6; ++j) {
                int t = t0 + j;
                float sx = ip[t] + al[t];     // same fp32 add as serial scan
                fires[j] = (sx >= 1.f) ? 1 : 0;
                cnt += fires[j];
            }
        }
        redI[tid] = cnt; __syncthreads();
        #pragma unroll
        for (int off = 1; off < 256; off <<= 1) {
            int v = redI[tid];
            if (tid >= off) v += redI[tid - off];
            __syncthreads();
            redI[tid] = v;
            __syncthreads();
        }
        if (t0 < T_) {
            int F = redI[tid] - cnt;
            const int base = b*T_;
            #pragma unroll
            for (int j = 0; j < 6; ++j) {
                int t = t0 + j;
                float a = al[t], ipv = ip[t];
                int fire = fires[j];
                F += fire;
                int tk1 = min(F, nm1);
                int tk0 = min(F - fire, nm1);
                float w0 = fire ? (1.f - ipv) : a;
                float w1 = (t < T_-1) ? (a - w0) : 0.f;
                tok0[base+t] = tk0;  w0a[base+t] = w0;
                tok1[base+t] = tk1;  w1a[base+t] = w1;
                if (tk1 != tk0) {
                    hi[b*MTOK + tk0] = t + 1;
                    lo[b*MTOK + tk1] = t;
                }
                if (t == T_-1) hi[b*MTOK + tk1] = T_;
            }
        }
    } else {
        // ================= transpose branch =================
        float (*tile)[33] = (float(*)[33])smem;
        int blk = blockIdx.x - B_;
        const float* src; u16* dst; int R, C, bx, by; bool scaled;
        if (blk < 1600) { src = cif_w;  dst = cwt; R = HM1; C = H_;   bx = blk % 40;  by = blk / 40;  scaled = false; }
        else { blk -= 1600; src = text_w; dst = twt; R = H_;  C = OUT_; bx = blk % 128; by = blk / 128; scaled = true; }
        int c0 = bx * 32, r0 = by * 32;
        int lx = tid & 31, ly = tid >> 5;  // 32 x 8
        #pragma unroll
        for (int j = 0; j < 4; ++j) {
            int r = r0 + ly + j*8;
            tile[ly + j*8][lx] = (r < R) ? src[(size_t)r*C + c0 + lx] : 0.f;
        }
        __syncthreads();
        // write value = src[r0+lx][c0+ly+j*8]; its k-index is r0+lx -> fold rms_w
        float rw = scaled ? rms_w[r0 + lx] : 1.f;
        #pragma unroll
        for (int j = 0; j < 4; ++j) {
            int c = c0 + ly + j*8;
            dst[(size_t)c*KPAD + r0 + lx] = f2bf(tile[lx][ly + j*8] * rw);
        }
    }
}

// K3: sparse pooling -> h1b bf16 [MROWS][KPAD], col 1279 = 0.
// Latency-optimized: weights staged to LDS, branchless float4 main loop.
__global__ __launch_bounds__(256) void k3_pool(
    const float* __restrict__ audio,
    const int* __restrict__ tok0, const float* __restrict__ w0a,
    const int* __restrict__ tok1, const float* __restrict__ w1a,
    const int* __restrict__ lo, const int* __restrict__ hi,
    u16* __restrict__ h1b)
{
    __shared__ float wl[1536];
    const int bm = blockIdx.x;
    const int b = bm / MTOK, m = bm % MTOK;
    const int l = lo[bm], h = hi[bm];
    const int tid = threadIdx.x;
    const int len = h - l;

    // stage combined weights (coalesced; removes scalar-load latency from loop)
    for (int j = tid; j < len; j += 256) {
        int i0 = b*T_ + l + j;
        float w = 0.f;
        if (tok0[i0] == m) w += w0a[i0];
        if (tok1[i0] == m) w += w1a[i0];
        wl[j] = w;
    }
    __syncthreads();

    const int d4 = tid * 4;          // covers 0..1023
    const int d1 = 1024 + tid;       // covers 1024..1279
    const float* rowp = audio + (size_t)(b*T_ + l) * H_;
    float4 acc4 = make_float4(0.f, 0.f, 0.f, 0.f);
    float acc1 = 0.f;
    #pragma unroll 4
    for (int j = 0; j < len; ++j) {
        float w = wl[j];
        const float* row = rowp + (size_t)j * H_;
        float4 r4 = *(const float4*)(row + d4);     // aligned: row stride 5120 B
        float r1 = (d1 < HM1) ? row[d1] : 0.f;
        acc4.x += w * r4.x; acc4.y += w * r4.y;
        acc4.z += w * r4.z; acc4.w += w * r4.w;
        acc1 += w * r1;
    }
    u16* dst = h1b + (size_t)bm * KPAD;
    ushort4 o;
    o.x = f2bf(acc4.x); o.y = f2bf(acc4.y); o.z = f2bf(acc4.z); o.w = f2bf(acc4.w);
    *(ushort4*)&dst[d4] = o;
    dst[d1] = (d1 < HM1) ? f2bf(acc1) : (u16)0;     // d1==1279 -> zero pad
}

// MFMA bf16 GEMM (B^T form), BK=32 (round-6 proven), 3 blocks/CU.
// CIF mode: bf16 out + per-row sum-of-squares atomics (pre-rounding fp32).
// TEXT mode: fp32 out, per-row 1/rms scale applied to acc (rms_w folded in Bt).
template<int TM, bool CIF>
__global__ __launch_bounds__(256, 3) void mfma_gemm_bt(
    const u16* __restrict__ A, const u16* __restrict__ Bt,
    const float* __restrict__ bias, void* __restrict__ Cv,
    float* __restrict__ h_sumsq, int M, int N)
{
    constexpr int K = KPAD;
    constexpr int RA = TM / 64;
    constexpr int MI = 4;
    constexpr int NI = (TM == 128) ? 4 : 2;
    __shared__ u16 sA[TM*32];
    __shared__ u16 sB[128*32];
    const int tid = threadIdx.x;
    const int m0 = blockIdx.y * TM, n0 = blockIdx.x * 128;
    const int wave = tid >> 6, lane = tid & 63;
    const int wm = (TM == 128) ? (wave & 1) * 64 : 0;
    const int wn = (TM == 128) ? (wave >> 1) * 64 : wave * 32;
    const int lrow = lane & 15, quad = lane >> 4;

    const int r0 = tid >> 2, sl = tid & 3;
    const int q0 = sl ^ (r0 & 3) ^ ((r0 >> 2) & 3);
    const u16* Ag[RA];
    #pragma unroll
    for (int p = 0; p < RA; ++p)
        Ag[p] = A + (size_t)min(m0 + r0 + 64*p, M - 1) * K + q0 * 8;
    const u16* Bg[2];
    #pragma unroll
    for (int p = 0; p < 2; ++p)
        Bg[p] = Bt + (size_t)(n0 + r0 + 64*p) * K + q0 * 8;

    int offA[MI], offB[NI];
    #pragma unroll
    for (int i = 0; i < MI; ++i) {
        int m = wm + i*16 + lrow;
        offA[i] = m*32 + (quad ^ (m & 3) ^ ((m >> 2) & 3)) * 8;
    }
    #pragma unroll
    for (int i = 0; i < NI; ++i) {
        int n = wn + i*16 + lrow;
        offB[i] = n*32 + (quad ^ (n & 3) ^ ((n >> 2) & 3)) * 8;
    }

    f32x4 acc[MI][NI] = {};

    for (int k0 = 0; k0 < K; k0 += 32) {
        #pragma unroll
        for (int p = 0; p < RA; ++p) glds16(Ag[p] + k0, sA + (tid + 256*p)*8);
        #pragma unroll
        for (int p = 0; p < 2;  ++p) glds16(Bg[p] + k0, sB + (tid + 256*p)*8);
        __syncthreads();
        bf16x8 af[MI], bfr[NI];
        #pragma unroll
        for (int i = 0; i < MI; ++i) af[i]  = *(const bf16x8*)&sA[offA[i]];
        #pragma unroll
        for (int i = 0; i < NI; ++i) bfr[i] = *(const bf16x8*)&sB[offB[i]];
        #pragma unroll
        for (int mi = 0; mi < MI; ++mi)
            #pragma unroll
            for (int ni = 0; ni < NI; ++ni)
                acc[mi][ni] = __builtin_amdgcn_mfma_f32_16x16x32_bf16(
                    af[mi], bfr[ni], acc[mi][ni], 0, 0, 0);
        __syncthreads();
    }

    // epilogue: C/D layout col=lane&15, row=quad*4+reg
    float bv[NI];
    #pragma unroll
    for (int ni = 0; ni < NI; ++ni) bv[ni] = bias[n0 + wn + ni*16 + lrow];

    #pragma unroll
    for (int mi = 0; mi < MI; ++mi) {
        #pragma unroll
        for (int r = 0; r < 4; ++r) {
            int row = m0 + wm + mi*16 + quad*4 + r;
            if (CIF) {
                float ss = 0.f;
                #pragma unroll
                for (int ni = 0; ni < NI; ++ni) {
                    float v = acc[mi][ni][r] + bv[ni];
                    ss += v * v;
                    if (row < M)
                        ((u16*)Cv)[(size_t)row*N + (n0 + wn + ni*16 + lrow)] = f2bf(v);
                }
                // reduce ss over the 16 lanes (lrow) sharing this row
                ss += __shfl_xor(ss, 1);
                ss += __shfl_xor(ss, 2);
                ss += __shfl_xor(ss, 4);
                ss += __shfl_xor(ss, 8);
                if (lrow == 0 && row < M) atomicAdd(&h_sumsq[row], ss);
            } else {
                float inv = 1.f;
                if (row < M)
                    inv = 1.f / sqrtf(h_sumsq[row] / (float)H_ + 1e-6f);
                #pragma unroll
                for (int ni = 0; ni < NI; ++ni) {
                    if (row < M)
                        ((float*)Cv)[(size_t)row*N + (n0 + wn + ni*16 + lrow)] =
                            acc[mi][ni][r] * inv + bv[ni];
                }
            }
        }
    }
}

extern "C" void kernel_launch(void* const* d_in, const int* in_sizes, int n_in,
                              void* d_out, int out_size, void* d_ws, size_t ws_size,
                              hipStream_t stream) {
    (void)in_sizes; (void)n_in; (void)out_size; (void)ws_size;
    const float* audio      = (const float*)d_in[0];
    const int*   num_tokens = (const int*)d_in[1];
    const float* rms_w      = (const float*)d_in[2];
    const float* cif_w      = (const float*)d_in[3];
    const float* cif_b      = (const float*)d_in[4];
    const float* text_w     = (const float*)d_in[5];
    const float* text_b     = (const float*)d_in[6];

    float* out  = (float*)d_out;                   // fp32 output
    float* pred = out + (size_t)MROWS * OUT_;      // pred_num_tokens tail (8 floats)

    char* ws = (char*)d_ws;
    float* h_sumsq = (float*)(ws + 0);         // 12000 B (zeroed in k_front)
    float* w0a  = (float*)(ws + 48000);
    float* w1a  = (float*)(ws + 96000);
    int*   tok0 = (int*)  (ws + 144000);
    int*   tok1 = (int*)  (ws + 192000);
    int*   lo   = (int*)  (ws + 240000);
    int*   hi   = (int*)  (ws + 252000);
    // DISJOINT regions (no lifetime aliasing):
    u16* h1b = (u16*)(ws + 264192);     //  7,680,000 B
    u16* cwt = (u16*)(ws + 7944192);    //  3,276,800 B
    u16* twt = (u16*)(ws + 11220992);   // 10,485,760 B  (rms_w folded in)
    u16* hX  = (u16*)(ws + 21706752);   //  7,680,000 B  (cif out, unnormalized)
    // total ws usage: 29,386,752 B

    // scan (blocks 0..7) + weight transposes (blocks 8..6727)
    k_front<<<B_ + 1600 + 5120, 256, 0, stream>>>(
        audio, num_tokens, rms_w, pred, tok0, w0a, tok1, w1a, lo, hi,
        h_sumsq, cif_w, text_w, cwt, twt);
    k3_pool<<<MROWS, 256, 0, stream>>>(audio, tok0, w0a, tok1, w1a, lo, hi, h1b);
    // cif_proj (bf16 out + row sumsq): hX = h1b . cwt^T + cif_b
    mfma_gemm_bt<64, true><<<dim3(H_/128, (MROWS+63)/64), 256, 0, stream>>>(
        h1b, cwt, cif_b, hX, h_sumsq, MROWS, H_);
    // text_proj (fp32 out, 1/rms applied in epilogue): out = norm(hX) . twt^T + text_b
    mfma_gemm_bt<128, false><<<dim3(OUT_/128, (MROWS+127)/128), 256, 0, stream>>>(
        hX, twt, text_b, out, h_sumsq, MROWS, OUT_);
}